// Round 8
// baseline (4344.732 us; speedup 1.0000x reference)
//
#include <hip/hip_runtime.h>

// FeedBack LSTM: 128 warmup + 31 AR steps, B=4096, UNITS=512, FEAT=12.
//  - AR feedback folded into weights: z = h@(U + Wd@W) + (b + bd@W) (exact).
//  - Per step: [4096,512]@[512,2048] bf16 MFMA GEMM fused with gate math.
//  - R3: pred via one MFMA kernel over stored h-history (hall ring).
//  - R4/R5: persistent kernel — REVERTED (lost to plain launches).
//  - R6/R7: B direct global->VGPR from fragment-major packed U^T (2 MB dense).
//  - R8: BARRIER-FREE K-loop. A also direct global->VGPR with MFMA lane
//    mapping (L1 dedups the wn-twin wave's identical loads; LDS A-staging
//    removed). Zero __syncthreads in the K-loop; 1-deep alternating register
//    sets; compiler-counted vmcnt. LDS only for the z-epilogue. Rationale:
//    R7 post-mortem showed 2 barrier drains/K-iter (16/step) cost ~15 us/step
//    against a 4.1 us MFMA floor.

typedef __bf16 bf16;
typedef __attribute__((ext_vector_type(8))) __bf16 bf16x8;
typedef __attribute__((ext_vector_type(4))) float f32x4;

#define NB    4096
#define TSEQ  128
#define FEAT  12
#define UNITS 512
#define NZ    2048
#define OUTS  32

#define BM 128
#define BK 64

// workspace layout (bytes)
#define OFF_UT   ((size_t)0)
#define OFF_UTA  (OFF_UT  + (size_t)NZ*UNITS*2)    // 2 MB  (packed U^T)
#define OFF_WT   (OFF_UTA + (size_t)NZ*UNITS*2)    // 2 MB  (packed (U+WdW)^T)
#define OFF_B2   (OFF_WT  + (size_t)NZ*32*2)       // 128 KB
#define OFF_WDT  (OFF_B2  + (size_t)NZ*4)          // 8 KB
#define OFF_H0   (OFF_WDT + (size_t)16*UNITS*2)    // 16 KB
#define OFF_H1   (OFF_H0  + (size_t)NB*UNITS*2)    // 4 MB
#define OFF_C    (OFF_H1  + (size_t)NB*UNITS*2)    // 4 MB
#define WS_NEED  (OFF_C   + (size_t)NB*UNITS*4)    // +8 MB
#define OFF_HALL (WS_NEED)
#define HALL_SL  ((size_t)NB*UNITS)
#define WS_BIG   (OFF_HALL + (size_t)OUTS*NB*UNITS*2)   // +128 MB

__device__ __forceinline__ float fast_exp2(float x){ return __builtin_amdgcn_exp2f(x); }
__device__ __forceinline__ float fast_rcp (float x){ return __builtin_amdgcn_rcpf(x); }
__device__ __forceinline__ float sigm_(float x){ return fast_rcp(1.f + fast_exp2(-1.4426950408889634f*x)); }
__device__ __forceinline__ float tanh_(float x){ return 1.f - 2.f*fast_rcp(1.f + fast_exp2(2.8853900817779268f*x)); }

// ---- fragment-major packed B layout (DENSE, 2 MB total) ----------------
//   lnl = wn*64+f*16+l15 (block-local col), n = gate<<9 | nu*32 + lnl>>2,
//   k = it*64 + kk*32 + kgrp*8 + e
//   frag = (((nu*2+wn)*4+f)*8 + it)*2 + kk          (0..2047)
//   byte = frag*1024 + kgrp*256 + l15*16 + e*2      (< 2 MB)
__device__ __forceinline__ size_t bp_off(int n, int k){
  int g  = n >> 9;             // gate
  int uc = n & 511;            // unit
  int nu = uc >> 5, uo = uc & 31;
  int lnl = uo*4 + g;
  int wn = lnl >> 6, f = (lnl >> 4) & 3, l15 = lnl & 15;
  int it = k >> 6, kk = (k >> 5) & 1, kgrp = (k >> 3) & 3, e = k & 7;
  int frag = (((nu*2 + wn)*4 + f)*8 + it)*2 + kk;
  return (size_t)frag*1024 + kgrp*256 + l15*16 + e*2;
}

// ---------------- prep: packed U^T and packed (U + Wd@W)^T --------------
__global__ void prep_u_kernel(const float* __restrict__ U, const float* __restrict__ W,
                              const float* __restrict__ Wd,
                              bf16* __restrict__ Utp, bf16* __restrict__ Utap){
  __shared__ float su[64][65];
  __shared__ float sa[64][65];
  const int n0 = blockIdx.x * 64;          // 32 blocks over N=2048
  const int k0 = blockIdx.y * 64;          // 8 blocks over K=512
  const int tx = threadIdx.x & 63;
  const int rr = threadIdx.x >> 6;
  #pragma unroll 4
  for (int it = 0; it < 16; ++it){
    int k = it*4 + rr;
    float u = U[(size_t)(k0+k)*NZ + n0 + tx];
    float a = u;
    #pragma unroll
    for (int j = 0; j < FEAT; ++j) a += Wd[(k0+k)*FEAT + j] * W[(size_t)j*NZ + n0 + tx];
    su[tx][k] = u;   // [n-local][k-local]
    sa[tx][k] = a;
  }
  __syncthreads();
  const int nl = threadIdx.x & 63;
  const int q  = threadIdx.x >> 6;
  const float (*src)[65] = (q & 1) ? sa : su;
  char* dst = (char*)((q & 1) ? Utap : Utp);
  const int kh = (q >> 1) * 32;
  #pragma unroll
  for (int kc = 0; kc < 32; kc += 8){
    bf16x8 v;
    #pragma unroll
    for (int e = 0; e < 8; ++e) v[e] = (bf16)src[nl][kh + kc + e];
    *reinterpret_cast<bf16x8*>(dst + bp_off(n0 + nl, k0 + kh + kc)) = v;
  }
}

// ------- prep: W^T (k-padded), b2 = b + bd@W, Wdt = Wd^T (bf16) ---------
__global__ void prep_w_kernel(const float* __restrict__ W, const float* __restrict__ b,
                              const float* __restrict__ bd, const float* __restrict__ Wd,
                              bf16* __restrict__ Wt, float* __restrict__ b2,
                              bf16* __restrict__ Wdt){
  const int n = blockIdx.x*256 + threadIdx.x;
  float acc = b[n];
  #pragma unroll
  for (int j = 0; j < FEAT; ++j){
    float w = W[(size_t)j*NZ + n];
    Wt[(size_t)n*32 + j] = (bf16)w;
    acc += bd[j] * w;
  }
  #pragma unroll
  for (int j = FEAT; j < 32; ++j) Wt[(size_t)n*32 + j] = (bf16)0.f;
  b2[n] = acc;
  if (n < UNITS){
    #pragma unroll
    for (int j = 0; j < FEAT; ++j) Wdt[(size_t)j*UNITS + n] = (bf16)Wd[(size_t)n*FEAT + j];
    #pragma unroll
    for (int j = FEAT; j < 16; ++j) Wdt[(size_t)j*UNITS + n] = (bf16)0.f;
  }
}

// ---------------- one LSTM step (fused GEMM + gates) --------------------
// grid 512 = 32 m-tiles x 16 unit-tiles, 256 threads (4 waves: 2 wm x 2 wn).
// Both operands direct global->VGPR; no barriers in the K-loop.
template<int HAS_X>
__launch_bounds__(256, 2)
__global__ void lstm_step_kernel(const bf16* __restrict__ hin, bf16* __restrict__ hout,
                                 float* __restrict__ c,
                                 const bf16* __restrict__ Bp,    // packed 2 MB
                                 const float* __restrict__ bias, // [2048]
                                 const float* __restrict__ xt,   // x + t*FEAT
                                 const bf16* __restrict__ Wt)    // [2048][32]
{
  __shared__ alignas(16) char lds[65536];   // z-epilogue only

  int bid = blockIdx.x;
  bid = (bid & 7) * 64 + (bid >> 3);          // XCD swizzle
  const int mt = bid >> 4;
  const int nu = bid & 15;
  const int m0 = mt * BM;

  const int tid  = threadIdx.x;
  const int lane = tid & 63;
  const int wid  = tid >> 6;
  const int wm   = wid >> 1, wn = wid & 1;
  const int l15  = lane & 15;
  const int kgrp = lane >> 4;

  // A direct-load base: lane -> h[(m0 + wm*64 + f*16 + l15)*512 + it*64 + kk*32 + kgrp*8]
  const bf16* ap = hin + (size_t)(m0 + wm*64 + l15)*UNITS + kgrp*8;
  // B packed base: + f*16384 + it*2048 + kk*1024 bytes per fragment
  const char* bp = (const char*)Bp + (size_t)(nu*2 + wn)*65536 + kgrp*256 + l15*16;

  f32x4 acc[4][4];
  #pragma unroll
  for (int i = 0; i < 4; ++i)
    #pragma unroll
    for (int j = 0; j < 4; ++j) acc[i][j] = f32x4{0.f,0.f,0.f,0.f};

  bf16x8 rA[2][8], rB[2][8];   // [set][f*2+kk]

  auto loadAB = [&](int s, int it){
    #pragma unroll
    for (int f = 0; f < 4; ++f)
      #pragma unroll
      for (int kk = 0; kk < 2; ++kk){
        rA[s][f*2+kk] = *reinterpret_cast<const bf16x8*>(ap + f*(16*UNITS) + it*BK + kk*32);
        rB[s][f*2+kk] = *reinterpret_cast<const bf16x8*>(bp + f*16384 + it*2048 + kk*1024);
      }
  };
  auto compute = [&](int s){
    #pragma unroll
    for (int kk = 0; kk < 2; ++kk)
      #pragma unroll
      for (int i = 0; i < 4; ++i)
        #pragma unroll
        for (int j = 0; j < 4; ++j)
          acc[i][j] = __builtin_amdgcn_mfma_f32_16x16x32_bf16(rA[s][i*2+kk], rB[s][j*2+kk], acc[i][j], 0, 0, 0);
  };

  const int eu  = tid & 31;
  const int erg = tid >> 5;
  const int cu  = nu*32 + eu;
  float bi_ = bias[0*UNITS + cu];
  float bf_ = bias[1*UNITS + cu];
  float bg_ = bias[2*UNITS + cu];
  float bo_ = bias[3*UNITS + cu];

  // prologue: set 0 + hoisted c-reads (consumed in epilogue, counted vmcnt)
  loadAB(0, 0);
  const int rbase = m0 + erg*16;
  float cold[16];
  {
    const float* cp = c + (size_t)rbase*UNITS + cu;
    #pragma unroll
    for (int r = 0; r < 16; ++r) cold[r] = cp[(size_t)r*UNITS];
  }

  bf16x8 xa[4], wq[4];
  // ---- barrier-free K-loop: consume set p, load set p^1 for t+1 ----
  #pragma unroll
  for (int t = 0; t < 8; ++t){
    const int p = t & 1;
    if (t < 7) loadAB(p ^ 1, t + 1);
    if (HAS_X && t == 7){
      // x / Wt fragments issued here: covered by compute(p), short live range
      #pragma unroll
      for (int f = 0; f < 4; ++f){
        int row = m0 + wm*64 + f*16 + l15;
        const float* xr = xt + (size_t)row * (TSEQ*FEAT);
        bf16x8 v;
        #pragma unroll
        for (int j = 0; j < 8; ++j) v[j] = (bf16)0.f;
        if (kgrp == 0){
          float4 a = *reinterpret_cast<const float4*>(xr);
          float4 b = *reinterpret_cast<const float4*>(xr + 4);
          v[0]=(bf16)a.x; v[1]=(bf16)a.y; v[2]=(bf16)a.z; v[3]=(bf16)a.w;
          v[4]=(bf16)b.x; v[5]=(bf16)b.y; v[6]=(bf16)b.z; v[7]=(bf16)b.w;
        } else if (kgrp == 1){
          float4 a = *reinterpret_cast<const float4*>(xr + 8);
          v[0]=(bf16)a.x; v[1]=(bf16)a.y; v[2]=(bf16)a.z; v[3]=(bf16)a.w;
        }
        xa[f] = v;
        int lnl = wn*64 + f*16 + l15;
        int zc  = ((lnl & 3) << 9) + nu*32 + (lnl >> 2);
        wq[f] = *reinterpret_cast<const bf16x8*>(Wt + (size_t)zc*32 + kgrp*8);
      }
    }
    compute(p);
  }

  if (HAS_X){
    #pragma unroll
    for (int i = 0; i < 4; ++i)
      #pragma unroll
      for (int j = 0; j < 4; ++j)
        acc[i][j] = __builtin_amdgcn_mfma_f32_16x16x32_bf16(xa[i], wq[j], acc[i][j], 0, 0, 0);
  }

  // ---- z through LDS: store transposed+swizzled, re-read all-lane ----
  // (LDS untouched before this point: no pre-store barrier needed)
  #pragma unroll
  for (int fm = 0; fm < 4; ++fm){
    #pragma unroll
    for (int fn = 0; fn < 4; ++fn){
      int col  = wn*64 + fn*16 + l15;
      int srow = wm*16 + fm*4 + kgrp;
      *reinterpret_cast<f32x4*>(lds + col*512 + ((srow ^ (col & 7)) << 4)) = acc[fm][fn];
    }
  }
  asm volatile("s_waitcnt lgkmcnt(0)" ::: "memory");
  __builtin_amdgcn_sched_barrier(0);
  __builtin_amdgcn_s_barrier();

  #pragma unroll
  for (int q = 0; q < 4; ++q){
    const int s = erg*4 + q;
    f32x4 zi = *reinterpret_cast<const f32x4*>(lds + (eu*4+0)*512 + ((s ^ ((eu*4+0)&7)) << 4));
    f32x4 zf = *reinterpret_cast<const f32x4*>(lds + (eu*4+1)*512 + ((s ^ ((eu*4+1)&7)) << 4));
    f32x4 zg = *reinterpret_cast<const f32x4*>(lds + (eu*4+2)*512 + ((s ^ ((eu*4+2)&7)) << 4));
    f32x4 zo = *reinterpret_cast<const f32x4*>(lds + (eu*4+3)*512 + ((s ^ ((eu*4+3)&7)) << 4));
    #pragma unroll
    for (int rr = 0; rr < 4; ++rr){
      int r = q*4 + rr;
      float iv = sigm_(zi[rr] + bi_);
      float fv = sigm_(zf[rr] + bf_);
      float gv = tanh_(zg[rr] + bg_);
      float ov = sigm_(zo[rr] + bo_);
      float cn = fv*cold[r] + iv*gv;
      size_t idx = (size_t)(rbase + r)*UNITS + cu;
      c[idx]    = cn;
      hout[idx] = (bf16)(ov*tanh_(cn));
    }
  }
}

// ------ pred: out[:, slot, :] = h_slot @ Wd + bd via 16x16x32 MFMA ------
__global__ void pred_all_kernel(const bf16* __restrict__ hbase, size_t slot_stride, int s0,
                                const bf16* __restrict__ Wdt,
                                const float* __restrict__ bd, float* __restrict__ out){
  const int slot = s0 + blockIdx.y;
  const bf16* h  = hbase + (size_t)blockIdx.y * slot_stride;
  const int tid = threadIdx.x, lane = tid & 63, wid = tid >> 6;
  const int l15 = lane & 15, kg = lane >> 4;
  const int r0 = blockIdx.x*64 + wid*16;
  f32x4 acc = f32x4{0.f,0.f,0.f,0.f};
  const bf16* ap = h   + (size_t)(r0 + l15)*UNITS + kg*8;
  const bf16* bp = Wdt + (size_t)l15*UNITS + kg*8;
  #pragma unroll
  for (int ks = 0; ks < 16; ++ks){
    bf16x8 a = *reinterpret_cast<const bf16x8*>(ap + ks*32);
    bf16x8 b = *reinterpret_cast<const bf16x8*>(bp + ks*32);
    acc = __builtin_amdgcn_mfma_f32_16x16x32_bf16(a, b, acc, 0, 0, 0);
  }
  if (l15 < FEAT){
    float bdv = bd[l15];
    #pragma unroll
    for (int r = 0; r < 4; ++r){
      int row = r0 + kg*4 + r;
      out[(size_t)row*(OUTS*FEAT) + slot*FEAT + l15] = acc[r] + bdv;
    }
  }
}

// ------------------------------------------------------------------------
extern "C" void kernel_launch(void* const* d_in, const int* in_sizes, int n_in,
                              void* d_out, int out_size, void* d_ws, size_t ws_size,
                              hipStream_t stream){
  const float* x  = (const float*)d_in[0];
  const float* W  = (const float*)d_in[1];
  const float* U  = (const float*)d_in[2];
  const float* b  = (const float*)d_in[3];
  const float* Wd = (const float*)d_in[4];
  const float* bd = (const float*)d_in[5];
  float* out = (float*)d_out;
  (void)in_sizes; (void)n_in; (void)out_size;
  if (ws_size < WS_NEED) return;
  const bool big = ws_size >= WS_BIG;

  char* ws  = (char*)d_ws;
  bf16* Utp = (bf16*)(ws + OFF_UT);
  bf16* Utap= (bf16*)(ws + OFF_UTA);
  bf16* Wt  = (bf16*)(ws + OFF_WT);
  float* b2 = (float*)(ws + OFF_B2);
  bf16* Wdt = (bf16*)(ws + OFF_WDT);
  bf16* h0  = (bf16*)(ws + OFF_H0);
  bf16* h1  = (bf16*)(ws + OFF_H1);
  float* c  = (float*)(ws + OFF_C);
  bf16* hall= (bf16*)(ws + OFF_HALL);

  hipMemsetAsync(h0, 0, (size_t)NB*UNITS*2, stream);
  hipMemsetAsync(c,  0, (size_t)NB*UNITS*4, stream);
  prep_u_kernel<<<dim3(32, 8), 256, 0, stream>>>(U, W, Wd, Utp, Utap);
  prep_w_kernel<<<8, 256, 0, stream>>>(W, b, bd, Wd, Wt, b2, Wdt);

  if (big){
    bf16* hcur = h0; bf16* hnxt = h1;
    for (int t = 0; t < TSEQ; ++t){
      bf16* dst = (t == TSEQ-1) ? hall : hnxt;
      lstm_step_kernel<1><<<512, 256, 0, stream>>>(hcur, dst, c, Utp, b, x + t*FEAT, Wt);
      hnxt = hcur; hcur = dst;
    }
    for (int s = 1; s < OUTS; ++s)
      lstm_step_kernel<0><<<512, 256, 0, stream>>>(hall + (size_t)(s-1)*HALL_SL,
                                                   hall + (size_t)s*HALL_SL,
                                                   c, Utap, b2, nullptr, nullptr);
    pred_all_kernel<<<dim3(NB/64, OUTS), 256, 0, stream>>>(hall, HALL_SL, 0, Wdt, bd, out);
  } else {
    bf16* hcur = h0; bf16* hnxt = h1;
    for (int t = 0; t < TSEQ; ++t){
      lstm_step_kernel<1><<<512, 256, 0, stream>>>(hcur, hnxt, c, Utp, b, x + t*FEAT, Wt);
      bf16* tmp = hcur; hcur = hnxt; hnxt = tmp;
    }
    pred_all_kernel<<<dim3(NB/64, 1), 256, 0, stream>>>(hcur, 0, 0, Wdt, bd, out);
    for (int s = 1; s < OUTS; ++s){
      lstm_step_kernel<0><<<512, 256, 0, stream>>>(hcur, hnxt, c, Utap, b2, nullptr, nullptr);
      bf16* tmp = hcur; hcur = hnxt; hnxt = tmp;
      pred_all_kernel<<<dim3(NB/64, 1), 256, 0, stream>>>(hcur, 0, s, Wdt, bd, out);
    }
  }
}